// Round 5
// baseline (141.310 us; speedup 1.0000x reference)
//
#include <hip/hip_runtime.h>
#include <hip/hip_bf16.h>

typedef float f32x4 __attribute__((ext_vector_type(4)));
typedef _Float16 f16x8 __attribute__((ext_vector_type(8)));
typedef int   int4v  __attribute__((ext_vector_type(4)));

#define LOG2E 1.44269504088896340736f
#define LN2   0.693147180559945309417f

// ---------------------------------------------------------------------------
// Kernel 1: q = x@Wq+bq, k = x@Wk+bk (-> fp16), v = x@Wv+bv (f32).
// 2 rows per block (512 blocks = 2/CU), 192 threads: wave m handles matrix m.
// ---------------------------------------------------------------------------
__global__ __launch_bounds__(192) void k_qkv(
    const float* __restrict__ x,
    const float* __restrict__ Wq, const float* __restrict__ bq,
    const float* __restrict__ Wk, const float* __restrict__ bk,
    const float* __restrict__ Wv, const float* __restrict__ bv,
    _Float16* __restrict__ qf, _Float16* __restrict__ kf,
    float* __restrict__ vout)
{
    const int row0 = blockIdx.x * 2;           // rows = b*512 + i, [0,1024)
    __shared__ __align__(16) float xr[2][512];
    const int tid = threadIdx.x;

    for (int i = tid; i < 256; i += 192)       // 2 rows * 512 f32 = 256 float4
        ((f32x4*)&xr[0][0])[i] = ((const f32x4*)(x + (size_t)row0 * 512))[i];
    __syncthreads();

    const int m = tid >> 6, f = tid & 63;
    const float* W    = (m == 0) ? Wq : (m == 1) ? Wk : Wv;
    const float bias  = ((m == 0) ? bq : (m == 1) ? bk : bv)[f];
    float a0 = bias, a1 = bias;
    #pragma unroll 8
    for (int d = 0; d < 512; ++d) {
        float w = W[(size_t)d * 64 + f];
        a0 = fmaf(xr[0][d], w, a0);
        a1 = fmaf(xr[1][d], w, a1);
    }
    if (m == 2) {
        vout[(size_t)(row0 + 0) * 64 + f] = a0;
        vout[(size_t)(row0 + 1) * 64 + f] = a1;
    } else {
        _Float16* dst = (m == 0) ? qf : kf;
        dst[(size_t)(row0 + 0) * 64 + f] = (_Float16)a0;
        dst[(size_t)(row0 + 1) * 64 + f] = (_Float16)a1;
    }
}

// ---------------------------------------------------------------------------
// Kernel 2: per (b, i-tile 16, j-tile 16): single online pass over 127 shifts.
// Per shift: conv tile via 2 chained fp16 MFMA on sliding windows of the
// reversed zero-padded K rows; branchless online-max softmax state update
// (one exp2 per term). Merge 4 wave chunks; s = ln2*(TA-127*(M+log2 SE)).
// ---------------------------------------------------------------------------
__device__ __forceinline__ void extract8(const int (&dk)[8], int r, f16x8 &out)
{
    union { int i[4]; f16x8 v; } u;
    const int p2 = r >> 1;
    #pragma unroll
    for (int i = 0; i < 4; ++i) {
        if (r & 1) {
            unsigned lo32 = (unsigned)dk[p2 + i];
            unsigned hi32 = (unsigned)dk[p2 + i + 1];
            u.i[i] = (int)((lo32 >> 16) | (hi32 << 16)); // v_alignbit
        } else {
            u.i[i] = dk[p2 + i];
        }
    }
    out = u.v;
}

__global__ __launch_bounds__(256, 8) void k_score(
    const _Float16* __restrict__ qf,
    const _Float16* __restrict__ kf,
    float* __restrict__ sout)
{
    const int jt = blockIdx.x, it = blockIdx.y, b = blockIdx.z;
    __shared__ __align__(16) _Float16 ldsQ[16][72];
    __shared__ __align__(16) _Float16 ldsK[16][200];
    __shared__ __align__(16) float t2[128];
    __shared__ __align__(16) float mbuf[3][256];

    const int tid = threadIdx.x;

    { // zero ldsK (incl. pads): 16*200*2B = 1600 ints
        int* kz = (int*)&ldsK[0][0];
        #pragma unroll
        for (int i = 0; i < 7; ++i) {
            int idx = tid + i * 256;
            if (idx < 1600) kz[idx] = 0;
        }
    }
    if (tid < 128) { // stage Q tile: 16 rows x 64 fp16 = 128 int4
        int r = tid >> 3, c8 = (tid & 7) << 3;
        *(int4v*)&ldsQ[r][c8] =
            *(const int4v*)(qf + ((size_t)(b * 512 + it * 16 + r) * 64 + c8));
    }
    if (tid < 127) { // scaler table indexed by shift s (t = 126 - s)
        int s = tid, t = 126 - s;
        float nd = (t < 64) ? (float)(t + 1) : (float)(127 - t);
        t2[s] = ((float)(t + 2) / nd) * LOG2E;
    }
    __syncthreads();
    { // stage K reversed: ldsK[r][126-c] = kf[j0+r][c], 16*64 = 1024 elems
        int idx = tid;
        #pragma unroll
        for (int i = 0; i < 4; ++i) {
            int r = idx >> 6, c = idx & 63;
            ldsK[r][126 - c] = kf[(size_t)(b * 512 + jt * 16 + r) * 64 + c];
            idx += 256;
        }
    }
    __syncthreads();

    const int wid = tid >> 6, lane = tid & 63;
    const int lrow = lane & 15, g = lane >> 4;

    f16x8 af[2];
    #pragma unroll
    for (int kc = 0; kc < 2; ++kc)
        af[kc] = *(const f16x8*)&ldsQ[lrow][kc * 32 + g * 8];

    const int s0 = wid * 32;
    const int s1 = (wid == 3) ? 127 : (s0 + 32);

    float mh[4], se[4], sa[4];
    #pragma unroll
    for (int p = 0; p < 4; ++p) { mh[p] = -3.0e38f; se[p] = 0.f; sa[p] = 0.f; }

    for (int s8 = s0; s8 < s1; s8 += 8) {
        int dk[2][8];
        #pragma unroll
        for (int kc = 0; kc < 2; ++kc) {
            const int off = s8 + kc * 32 + g * 8;
            const int4v* kp = (const int4v*)&ldsK[lrow][off];
            int4v lo = kp[0];
            int4v hi = kp[1];
            #pragma unroll
            for (int i = 0; i < 4; ++i) {
                dk[kc][i]     = lo[i];
                dk[kc][4 + i] = hi[i];
            }
        }
        #pragma unroll
        for (int r = 0; r < 8; ++r) {
            if (s8 + r < s1) {
                f16x8 b0, b1;
                extract8(dk[0], r, b0);
                extract8(dk[1], r, b1);
                const f32x4 zf = {0.f, 0.f, 0.f, 0.f};
                f32x4 c = __builtin_amdgcn_mfma_f32_16x16x32_f16(af[0], b0, zf, 0, 0, 0);
                c = __builtin_amdgcn_mfma_f32_16x16x32_f16(af[1], b1, c, 0, 0, 0);
                const float t2v = t2[s8 + r];
                #pragma unroll
                for (int rr = 0; rr < 4; ++rr) {
                    float av = c[rr] * t2v;
                    float mold = mh[rr];
                    float mnew = fmaxf(mold, av);
                    float e = exp2f(-fabsf(av - mold));
                    bool up = av > mold;
                    se[rr] = fmaf(se[rr], up ? e : 1.0f, up ? 1.0f : e);
                    mh[rr] = mnew;
                    sa[rr] += av;
                }
            }
        }
    }

    // sequential cross-wave merge of (max, sumexp2, sum-arg)
    for (int w = 0; w < 4; ++w) {
        if (wid == w) {
            #pragma unroll
            for (int rr = 0; rr < 4; ++rr) {
                const int il = g * 4 + rr;
                const int jl = lrow;
                const int pi = il * 16 + jl;
                if (w == 0) {
                    mbuf[0][pi] = mh[rr]; mbuf[1][pi] = se[rr]; mbuf[2][pi] = sa[rr];
                } else {
                    float Mo = mbuf[0][pi];
                    float M  = fmaxf(Mo, mh[rr]);
                    mbuf[0][pi] = M;
                    mbuf[1][pi] = mbuf[1][pi] * exp2f(Mo - M) + se[rr] * exp2f(mh[rr] - M);
                    mbuf[2][pi] += sa[rr];
                }
            }
        }
        __syncthreads();
    }
    { // write 16x16 tile
        int pi = tid;
        if (pi < 256) {
            float M = mbuf[0][pi], SE = mbuf[1][pi], TA = mbuf[2][pi];
            float sv = LN2 * (TA - 127.0f * (M + log2f(SE)));
            int il = pi >> 4, jl = pi & 15;
            sout[(size_t)(b * 512 + it * 16 + il) * 512 + jt * 16 + jl] = sv;
        }
    }
}

// ---------------------------------------------------------------------------
// Kernel 3: p = s @ v  (512-reduction, j-split over 2 wave-groups),
// then out = p @ Wp + bp. 4 rows per block, 512 threads, grid 256.
// ---------------------------------------------------------------------------
__global__ __launch_bounds__(512) void k_pv(
    const float* __restrict__ s, const float* __restrict__ v,
    const float* __restrict__ Wp, const float* __restrict__ bp,
    float* __restrict__ out)
{
    const int tid = threadIdx.x;
    const int l = tid & 63, w = tid >> 6;     // 8 waves
    const int r = w & 3, h = w >> 2;          // row-in-block, j-half
    const int row = blockIdx.x * 4 + r;       // [0,1024)
    const int b = row >> 9;
    const float* srow = s + (size_t)row * 512 + h * 256;
    const float* vb   = v + (size_t)b * 512 * 64 + (size_t)h * 256 * 64;
    float acc = 0.f;
    #pragma unroll 8
    for (int j = 0; j < 256; ++j)
        acc = fmaf(srow[j], vb[(size_t)j * 64 + l], acc);

    __shared__ float pb[2][4][64];
    pb[h][r][l] = acc;
    __syncthreads();

    if (tid < 256) {
        int rr = tid >> 6, ll = tid & 63;
        pb[0][rr][ll] = pb[0][rr][ll] + pb[1][rr][ll];
    }
    __syncthreads();

    if (tid < 256) {
        int rr = tid >> 6, ll = tid & 63;
        float o = bp[ll];
        #pragma unroll 8
        for (int jj = 0; jj < 64; ++jj)
            o = fmaf(pb[0][rr][jj], Wp[(size_t)jj * 64 + ll], o);
        out[(size_t)(blockIdx.x * 4 + rr) * 64 + ll] = o;
    }
}

// ---------------------------------------------------------------------------
extern "C" void kernel_launch(void* const* d_in, const int* in_sizes, int n_in,
                              void* d_out, int out_size, void* d_ws, size_t ws_size,
                              hipStream_t stream)
{
    const float* x  = (const float*)d_in[0];
    const float* Wq = (const float*)d_in[1];
    const float* bq = (const float*)d_in[2];
    const float* Wk = (const float*)d_in[3];
    const float* bk = (const float*)d_in[4];
    const float* Wv = (const float*)d_in[5];
    const float* bv = (const float*)d_in[6];
    const float* Wp = (const float*)d_in[7];
    const float* bp = (const float*)d_in[8];
    float* out = (float*)d_out;

    char* ws = (char*)d_ws;
    _Float16* qf = (_Float16*)(ws + 0 * 131072);
    _Float16* kf = (_Float16*)(ws + 1 * 131072);
    float* vws = (float*)(ws + 2 * 131072);                 // 262144 B
    float* sws = (float*)(ws + 2 * 131072 + 262144);        // 2097152 B

    k_qkv<<<dim3(512), dim3(192), 0, stream>>>(x, Wq, bq, Wk, bk, Wv, bv,
                                               qf, kf, vws);
    k_score<<<dim3(32, 32, 2), dim3(256), 0, stream>>>(qf, kf, sws);
    k_pv<<<dim3(256), dim3(512), 0, stream>>>(sws, vws, Wp, bp, out);
}

// Round 7
// 63.870 us; speedup vs baseline: 2.2124x; 2.2124x over previous
//
#include <hip/hip_runtime.h>
#include <hip/hip_bf16.h>

typedef float f32x4 __attribute__((ext_vector_type(4)));
typedef _Float16 f16x8 __attribute__((ext_vector_type(8)));
typedef int   int4v  __attribute__((ext_vector_type(4)));

#define LOG2E 1.44269504088896340736f
#define LN2   0.693147180559945309417f

// ---------------------------------------------------------------------------
// Kernel 1: q = x@Wq+bq, k = x@Wk+bk (-> fp16), v = x@Wv+bv (f32).
// 2 rows per block (512 blocks = 2/CU), 192 threads: wave m handles matrix m.
// ---------------------------------------------------------------------------
__global__ __launch_bounds__(192) void k_qkv(
    const float* __restrict__ x,
    const float* __restrict__ Wq, const float* __restrict__ bq,
    const float* __restrict__ Wk, const float* __restrict__ bk,
    const float* __restrict__ Wv, const float* __restrict__ bv,
    _Float16* __restrict__ qf, _Float16* __restrict__ kf,
    float* __restrict__ vout)
{
    const int row0 = blockIdx.x * 2;           // rows = b*512 + i, [0,1024)
    __shared__ __align__(16) float xr[2][512];
    const int tid = threadIdx.x;

    for (int i = tid; i < 256; i += 192)       // 2 rows * 512 f32 = 256 float4
        ((f32x4*)&xr[0][0])[i] = ((const f32x4*)(x + (size_t)row0 * 512))[i];
    __syncthreads();

    const int m = tid >> 6, f = tid & 63;
    const float* W    = (m == 0) ? Wq : (m == 1) ? Wk : Wv;
    const float bias  = ((m == 0) ? bq : (m == 1) ? bk : bv)[f];
    float a0 = bias, a1 = bias;
    #pragma unroll 8
    for (int d = 0; d < 512; ++d) {
        float w = W[(size_t)d * 64 + f];
        a0 = fmaf(xr[0][d], w, a0);
        a1 = fmaf(xr[1][d], w, a1);
    }
    if (m == 2) {
        vout[(size_t)(row0 + 0) * 64 + f] = a0;
        vout[(size_t)(row0 + 1) * 64 + f] = a1;
    } else {
        _Float16* dst = (m == 0) ? qf : kf;
        dst[(size_t)(row0 + 0) * 64 + f] = (_Float16)a0;
        dst[(size_t)(row0 + 1) * 64 + f] = (_Float16)a1;
    }
}

// ---------------------------------------------------------------------------
// Kernel 2: per (b, i-tile 32, j-tile 16): SINGLE online pass over 127 shifts.
// Per shift: conv tile via chained fp16 MFMA (2 per i-half) on sliding windows
// of reversed zero-padded K rows; branchless online-max softmax state update
// (one exp2 per term). Merge 4 wave chunks; s = ln2*(TA-127*(M+log2 SE)).
// __launch_bounds__(256,4): 128-VGPR budget — (256,8) forced 32 VGPRs and
// spilled ~130 MB to scratch (round 5: WRITE_SIZE 106 MB, 3x slowdown).
// ---------------------------------------------------------------------------
__device__ __forceinline__ void extract8(const int (&dk)[8], int r, f16x8 &out)
{
    union { int i[4]; f16x8 v; } u;
    const int p2 = r >> 1;
    #pragma unroll
    for (int i = 0; i < 4; ++i) {
        if (r & 1) {
            unsigned lo32 = (unsigned)dk[p2 + i];
            unsigned hi32 = (unsigned)dk[p2 + i + 1];
            u.i[i] = (int)((lo32 >> 16) | (hi32 << 16)); // v_alignbit
        } else {
            u.i[i] = dk[p2 + i];
        }
    }
    out = u.v;
}

__global__ __launch_bounds__(256, 4) void k_score(
    const _Float16* __restrict__ qf,
    const _Float16* __restrict__ kf,
    float* __restrict__ sout)
{
    const int jt = blockIdx.x, it = blockIdx.y, b = blockIdx.z;
    __shared__ __align__(16) _Float16 ldsQ[32][72];
    __shared__ __align__(16) _Float16 ldsK[16][200];
    __shared__ __align__(16) float t2[128];
    __shared__ __align__(16) float mbuf[3][512];

    const int tid = threadIdx.x;

    { // zero ldsK (incl. pads): 16*200*2B = 1600 ints
        int* kz = (int*)&ldsK[0][0];
        #pragma unroll
        for (int i = 0; i < 7; ++i) {
            int idx = tid + i * 256;
            if (idx < 1600) kz[idx] = 0;
        }
    }
    { // stage Q tile: 32 rows x 64 fp16 = 256 int4
        int r = tid >> 3, c8 = (tid & 7) << 3;
        *(int4v*)&ldsQ[r][c8] =
            *(const int4v*)(qf + ((size_t)(b * 512 + it * 32 + r) * 64 + c8));
    }
    if (tid < 127) { // scaler table indexed by shift s (t = 126 - s)
        int s = tid, t = 126 - s;
        float nd = (t < 64) ? (float)(t + 1) : (float)(127 - t);
        t2[s] = ((float)(t + 2) / nd) * LOG2E;
    }
    __syncthreads();
    { // stage K reversed: ldsK[r][126-c] = kf[j0+r][c], 16*64 = 1024 elems
        int idx = tid;
        #pragma unroll
        for (int i = 0; i < 4; ++i) {
            int r = idx >> 6, c = idx & 63;
            ldsK[r][126 - c] = kf[(size_t)(b * 512 + jt * 16 + r) * 64 + c];
            idx += 256;
        }
    }
    __syncthreads();

    const int wid = tid >> 6, lane = tid & 63;
    const int lrow = lane & 15, g = lane >> 4;

    f16x8 af[2][2];
    #pragma unroll
    for (int ih = 0; ih < 2; ++ih)
        #pragma unroll
        for (int kc = 0; kc < 2; ++kc)
            af[ih][kc] = *(const f16x8*)&ldsQ[ih * 16 + lrow][kc * 32 + g * 8];

    const int s0 = wid * 32;
    const int s1 = (wid == 3) ? 127 : (s0 + 32);

    float mh[8], se[8], sa[8];
    #pragma unroll
    for (int p = 0; p < 8; ++p) { mh[p] = -3.0e38f; se[p] = 0.f; sa[p] = 0.f; }

    for (int s8 = s0; s8 < s1; s8 += 8) {
        f32x4 tt0 = *(const f32x4*)&t2[s8];
        f32x4 tt1 = *(const f32x4*)&t2[s8 + 4];
        int dk[2][8];
        #pragma unroll
        for (int kc = 0; kc < 2; ++kc) {
            const int off = s8 + kc * 32 + g * 8;
            const int4v* kp = (const int4v*)&ldsK[lrow][off];
            int4v lo = kp[0];
            int4v hi = kp[1];
            #pragma unroll
            for (int i = 0; i < 4; ++i) {
                dk[kc][i]     = lo[i];
                dk[kc][4 + i] = hi[i];
            }
        }
        #pragma unroll
        for (int r = 0; r < 8; ++r) {
            if (s8 + r < s1) {
                f16x8 b0, b1;
                extract8(dk[0], r, b0);
                extract8(dk[1], r, b1);
                const f32x4 zf = {0.f, 0.f, 0.f, 0.f};
                f32x4 acc[2];
                #pragma unroll
                for (int ih = 0; ih < 2; ++ih) {
                    f32x4 c = __builtin_amdgcn_mfma_f32_16x16x32_f16(af[ih][0], b0, zf, 0, 0, 0);
                    acc[ih]  = __builtin_amdgcn_mfma_f32_16x16x32_f16(af[ih][1], b1, c, 0, 0, 0);
                }
                const float t2v = (r < 4) ? tt0[r & 3] : tt1[r & 3];
                #pragma unroll
                for (int ih = 0; ih < 2; ++ih)
                    #pragma unroll
                    for (int rr = 0; rr < 4; ++rr) {
                        const int p = ih * 4 + rr;
                        float av = acc[ih][rr] * t2v;
                        float mold = mh[p];
                        float e = exp2f(-fabsf(av - mold));
                        bool up = av > mold;
                        se[p] = fmaf(se[p], up ? e : 1.0f, up ? 1.0f : e);
                        mh[p] = fmaxf(mold, av);
                        sa[p] += av;
                    }
            }
        }
    }

    // sequential cross-wave merge of (max, sumexp2, sum-arg)
    for (int w = 0; w < 4; ++w) {
        if (wid == w) {
            #pragma unroll
            for (int p = 0; p < 8; ++p) {
                const int ih = p >> 2, rr = p & 3;
                const int il = ih * 16 + g * 4 + rr;
                const int jl = lrow;
                const int pi = il * 16 + jl;
                if (w == 0) {
                    mbuf[0][pi] = mh[p]; mbuf[1][pi] = se[p]; mbuf[2][pi] = sa[p];
                } else {
                    float Mo = mbuf[0][pi];
                    float M  = fmaxf(Mo, mh[p]);
                    mbuf[0][pi] = M;
                    mbuf[1][pi] = mbuf[1][pi] * exp2f(Mo - M) + se[p] * exp2f(mh[p] - M);
                    mbuf[2][pi] += sa[p];
                }
            }
        }
        __syncthreads();
    }
    #pragma unroll
    for (int k2 = 0; k2 < 2; ++k2) {
        int pi = tid + k2 * 256;
        float M = mbuf[0][pi], SE = mbuf[1][pi], TA = mbuf[2][pi];
        float sv = LN2 * (TA - 127.0f * (M + log2f(SE)));
        int il = pi >> 4, jl = pi & 15;
        sout[(size_t)(b * 512 + it * 32 + il) * 512 + jt * 16 + jl] = sv;
    }
}

// ---------------------------------------------------------------------------
// Kernel 3: p = s @ v  (512-reduction, j-split over 2 wave-groups),
// then out = p @ Wp + bp. 4 rows per block, 512 threads, grid 256.
// ---------------------------------------------------------------------------
__global__ __launch_bounds__(512) void k_pv(
    const float* __restrict__ s, const float* __restrict__ v,
    const float* __restrict__ Wp, const float* __restrict__ bp,
    float* __restrict__ out)
{
    const int tid = threadIdx.x;
    const int l = tid & 63, w = tid >> 6;     // 8 waves
    const int r = w & 3, h = w >> 2;          // row-in-block, j-half
    const int row = blockIdx.x * 4 + r;       // [0,1024)
    const int b = row >> 9;
    const float* srow = s + (size_t)row * 512 + h * 256;
    const float* vb   = v + (size_t)b * 512 * 64 + (size_t)h * 256 * 64;
    float acc = 0.f;
    #pragma unroll 8
    for (int j = 0; j < 256; ++j)
        acc = fmaf(srow[j], vb[(size_t)j * 64 + l], acc);

    __shared__ float pb[2][4][64];
    pb[h][r][l] = acc;
    __syncthreads();

    if (tid < 256) {
        int rr = tid >> 6, ll = tid & 63;
        pb[0][rr][ll] = pb[0][rr][ll] + pb[1][rr][ll];
    }
    __syncthreads();

    if (tid < 256) {
        int rr = tid >> 6, ll = tid & 63;
        float o = bp[ll];
        #pragma unroll 8
        for (int jj = 0; jj < 64; ++jj)
            o = fmaf(pb[0][rr][jj], Wp[(size_t)jj * 64 + ll], o);
        out[(size_t)(blockIdx.x * 4 + rr) * 64 + ll] = o;
    }
}

// ---------------------------------------------------------------------------
extern "C" void kernel_launch(void* const* d_in, const int* in_sizes, int n_in,
                              void* d_out, int out_size, void* d_ws, size_t ws_size,
                              hipStream_t stream)
{
    const float* x  = (const float*)d_in[0];
    const float* Wq = (const float*)d_in[1];
    const float* bq = (const float*)d_in[2];
    const float* Wk = (const float*)d_in[3];
    const float* bk = (const float*)d_in[4];
    const float* Wv = (const float*)d_in[5];
    const float* bv = (const float*)d_in[6];
    const float* Wp = (const float*)d_in[7];
    const float* bp = (const float*)d_in[8];
    float* out = (float*)d_out;

    char* ws = (char*)d_ws;
    _Float16* qf = (_Float16*)(ws + 0 * 131072);
    _Float16* kf = (_Float16*)(ws + 1 * 131072);
    float* vws = (float*)(ws + 2 * 131072);                 // 262144 B
    float* sws = (float*)(ws + 2 * 131072 + 262144);        // 2097152 B

    k_qkv<<<dim3(512), dim3(192), 0, stream>>>(x, Wq, bq, Wk, bk, Wv, bv,
                                               qf, kf, vws);
    k_score<<<dim3(32, 16, 2), dim3(256), 0, stream>>>(qf, kf, sws);
    k_pv<<<dim3(256), dim3(512), 0, stream>>>(sws, vws, Wp, bp, out);
}